// Round 8
// baseline (83.678 us; speedup 1.0000x reference)
//
#include <hip/hip_runtime.h>

// B=32, G=512
// out layout: [rel_pos (B,G,G,3) | rel_ori (B,G,G,3,3)] flat f32
//
// Persistent sequential-stream version of R7:
//  - 2048 blocks (= 8 blocks/CU x 256 CU, all resident), 256 thr, 12 KB LDS
//  - block p owns rows bi = 8p .. 8p+7, processed in order; its writes form
//    two long sequential streams (48 KB pos, 144 KB ori) instead of 16
//    scattered one-shot windows -> fill-like DRAM row locality
//  - b is block-uniform (512 % 8 == 0); per-thread j inputs repeat each
//    iteration -> L1 hits
//  - inner iter: compute -> ds_write -> sync -> float4 writeback -> sync

#define G_ 512
#define NB 32

__global__ __launch_bounds__(256, 8) void relposori_kernel(
    const float* __restrict__ center,   // (B,G,6)
    const float* __restrict__ lrf,      // (B,G,3,3)
    float* __restrict__ out_pos,        // (B,G,G,3)
    float* __restrict__ out_ori)        // (B,G,G,3,3)
{
    __shared__ float s[3072];           // 12 KB: [0,768) pos | [768,3072) ori
    float* s_pos = s;
    float* s_ori = s + 768;

    int tid = threadIdx.x;
    int p   = blockIdx.x;               // 0..2047
    int bi0 = p << 3;                   // first of 8 consecutive rows
    int b   = bi0 >> 9;                 // block-uniform batch index

    const float* cb = center + (size_t)b * (G_ * 6);
    const float* lb = lrf    + (size_t)b * (G_ * 9);

    for (int rr = 0; rr < 8; ++rr) {
        int bi = bi0 + rr;

        // row-uniform inputs (scalar loads)
        const float* ci = center + (size_t)bi * 6;
        const float* li = lrf    + (size_t)bi * 9;
        float ci0 = ci[0], ci1 = ci[1], ci2 = ci[2];
        float li_[9];
#pragma unroll
        for (int t = 0; t < 9; ++t) li_[t] = li[t];

#pragma unroll
        for (int half = 0; half < 2; ++half) {
            int j = (half << 8) | tid;
            const float* cj = cb + j * 6;   // same addr every rr -> L1 hit
            const float* lj = lb + j * 9;
            float d0 = cj[0] - ci0, d1 = cj[1] - ci1, d2 = cj[2] - ci2;
            float lj_[9];
#pragma unroll
            for (int t = 0; t < 9; ++t) lj_[t] = lj[t];

            // rel_pos[k] = sum_c d[c] * lrf_i[c][k]
#pragma unroll
            for (int k = 0; k < 3; ++k)
                s_pos[tid * 3 + k] = d0 * li_[k] + d1 * li_[3 + k] + d2 * li_[6 + k];

            // rel_ori[m][n] = sum_k lrf_i[k][m] * lrf_j[k][n]
#pragma unroll
            for (int m = 0; m < 3; ++m)
#pragma unroll
                for (int n = 0; n < 3; ++n)
                    s_ori[tid * 9 + m * 3 + n] = li_[m]     * lj_[n]
                                               + li_[3 + m] * lj_[3 + n]
                                               + li_[6 + m] * lj_[6 + n];

            __syncthreads();

            // Fused float4 writeback: 768 f4 = 3 per thread; the t<192
            // split is at a wave boundary (no intra-wave divergence).
            const float4* s4 = (const float4*)s;
            float4* op4 = (float4*)out_pos + ((size_t)bi * 384  + (size_t)half * 192);
            float4* oo4 = (float4*)out_ori + ((size_t)bi * 1152 + (size_t)half * 576);
#pragma unroll
            for (int it = 0; it < 3; ++it) {
                int t = tid + (it << 8);
                if (t < 192) op4[t]       = s4[t];
                else         oo4[t - 192] = s4[t];
            }

            __syncthreads();   // WAR: next iter's ds_writes wait for reads
        }
    }
}

extern "C" void kernel_launch(void* const* d_in, const int* in_sizes, int n_in,
                              void* d_out, int out_size, void* d_ws, size_t ws_size,
                              hipStream_t stream) {
    const float* center = (const float*)d_in[0];
    const float* lrf    = (const float*)d_in[1];
    float* out = (float*)d_out;

    const int B = 32;
    const size_t n_pos = (size_t)B * G_ * G_ * 3;   // 25,165,824 floats
    float* out_pos = out;
    float* out_ori = out + n_pos;

    dim3 grid(2048);    // 8 rows per block, zero tail
    dim3 block(256);
    hipLaunchKernelGGL(relposori_kernel, grid, block, 0, stream,
                       center, lrf, out_pos, out_ori);
}

// Round 9
// 78.093 us; speedup vs baseline: 1.0715x; 1.0715x over previous
//
#include <hip/hip_runtime.h>

// B=32, G=512
// out layout: [rel_pos (B,G,G,3) | rel_ori (B,G,G,3,3)] flat f32
//
// R7 structure (best so far: 71.2 us) + non-temporal writeback stores.
//  - each one-shot block owns a HALF row: (b,i, 256 j's) -> LDS 12 KB
//  - 256 thr/block, 1 j per thread; 8 blocks/CU = 32 waves/CU resident
//  - compute -> ds_write -> __syncthreads -> 3x nontemporal float4
//    stores/thread (wave-aligned pos/ori split), then block ends
//    (stores drain async after s_endpgm; no vmcnt barrier ever).

#define G_ 512
#define NB 32

typedef float f4v __attribute__((ext_vector_type(4)));

__global__ __launch_bounds__(256, 8) void relposori_kernel(
    const float* __restrict__ center,   // (B,G,6)
    const float* __restrict__ lrf,      // (B,G,3,3)
    float* __restrict__ out_pos,        // (B,G,G,3)
    float* __restrict__ out_ori)        // (B,G,G,3,3)
{
    __shared__ float s[3072];           // 12 KB: [0,768) pos | [768,3072) ori
    float* s_pos = s;
    float* s_ori = s + 768;

    int blk  = blockIdx.x;
    int half = blk & 1;
    int bi   = blk >> 1;                // b*512 + i (uniform)
    int b    = bi >> 9;
    int tid  = threadIdx.x;
    int j    = (half << 8) | tid;

    // uniform (scalar) loads: center_i, lrf_i
    const float* ci = center + (size_t)bi * 6;
    const float* li = lrf    + (size_t)bi * 9;
    float ci0 = ci[0], ci1 = ci[1], ci2 = ci[2];
    float li_[9];
#pragma unroll
    for (int t = 0; t < 9; ++t) li_[t] = li[t];

    // per-thread j inputs (L1/L2-resident)
    size_t bj = (size_t)b * G_ + (size_t)j;
    const float* cj = center + bj * 6;
    const float* lj = lrf    + bj * 9;
    float d0 = cj[0] - ci0, d1 = cj[1] - ci1, d2 = cj[2] - ci2;
    float lj_[9];
#pragma unroll
    for (int t = 0; t < 9; ++t) lj_[t] = lj[t];

    // rel_pos[k] = sum_c d[c] * lrf_i[c][k]
#pragma unroll
    for (int k = 0; k < 3; ++k)
        s_pos[tid * 3 + k] = d0 * li_[k] + d1 * li_[3 + k] + d2 * li_[6 + k];

    // rel_ori[m][n] = sum_k lrf_i[k][m] * lrf_j[k][n]
#pragma unroll
    for (int m = 0; m < 3; ++m)
#pragma unroll
        for (int n = 0; n < 3; ++n)
            s_ori[tid * 9 + m * 3 + n] = li_[m]     * lj_[n]
                                       + li_[3 + m] * lj_[3 + n]
                                       + li_[6 + m] * lj_[6 + n];

    __syncthreads();

    // Fused writeback: 768 float4 total = 3 per thread, non-temporal
    // (output is write-once streaming data; don't pollute L2).
    // t in [0,192): pos; t in [192,768): ori. The split at t=192 is a
    // wave boundary -> no intra-wave divergence.
    const f4v* s4  = (const f4v*)s;
    f4v* op4 = (f4v*)out_pos + ((size_t)bi * 384  + (size_t)half * 192);
    f4v* oo4 = (f4v*)out_ori + ((size_t)bi * 1152 + (size_t)half * 576);

#pragma unroll
    for (int it = 0; it < 3; ++it) {
        int t = tid + (it << 8);
        if (t < 192) __builtin_nontemporal_store(s4[t], &op4[t]);
        else         __builtin_nontemporal_store(s4[t], &oo4[t - 192]);
    }
}

extern "C" void kernel_launch(void* const* d_in, const int* in_sizes, int n_in,
                              void* d_out, int out_size, void* d_ws, size_t ws_size,
                              hipStream_t stream) {
    const float* center = (const float*)d_in[0];
    const float* lrf    = (const float*)d_in[1];
    float* out = (float*)d_out;

    const int B = 32;
    const size_t n_pos = (size_t)B * G_ * G_ * 3;   // 25,165,824 floats
    float* out_pos = out;
    float* out_ori = out + n_pos;

    dim3 grid(B * G_ * 2);   // 32768 one-shot half-row blocks
    dim3 block(256);
    hipLaunchKernelGGL(relposori_kernel, grid, block, 0, stream,
                       center, lrf, out_pos, out_ori);
}

// Round 10
// 73.885 us; speedup vs baseline: 1.1325x; 1.0570x over previous
//
#include <hip/hip_runtime.h>

// B=32, G=512
// out layout: [rel_pos (B,G,G,3) | rel_ori (B,G,G,3,3)] flat f32
//
// R7 structure, quarter-row granularity + explicit wide input loads:
//  - each one-shot block owns a QUARTER row: (b,i, 128 j's) -> 6 KB LDS
//  - 128 thr/block (2 waves), 1 j per thread; 16 blocks/CU = 32 waves/CU
//  - inputs loaded wide: lj as f4+f4+f1, cj as one (overlapping) f4
//  - compute -> ds_write -> sync -> 3x float4 stores/thread, block ends
//    (stores drain async after s_endpgm; no vmcnt barrier)

#define G_ 512
#define NB 32

typedef float f4v __attribute__((ext_vector_type(4)));
typedef float f4u __attribute__((ext_vector_type(4), aligned(4)));

__global__ __launch_bounds__(128, 8) void relposori_kernel(
    const float* __restrict__ center,   // (B,G,6)
    const float* __restrict__ lrf,      // (B,G,3,3)
    float* __restrict__ out_pos,        // (B,G,G,3)
    float* __restrict__ out_ori)        // (B,G,G,3,3)
{
    __shared__ float s[1536];           // 6 KB: [0,384) pos | [384,1536) ori
    float* s_pos = s;
    float* s_ori = s + 384;

    int blk = blockIdx.x;
    int q   = blk & 3;                  // quarter index
    int bi  = blk >> 2;                 // b*512 + i (uniform)
    int b   = bi >> 9;
    int tid = threadIdx.x;
    int j   = (q << 7) | tid;

    // uniform (scalar) loads: center_i, lrf_i
    const float* ci = center + (size_t)bi * 6;
    const float* li = lrf    + (size_t)bi * 9;
    float ci0 = ci[0], ci1 = ci[1], ci2 = ci[2];
    float li_[9];
#pragma unroll
    for (int t = 0; t < 9; ++t) li_[t] = li[t];

    // per-thread j inputs, wide loads (L1/L2-resident)
    size_t bj = (size_t)b * G_ + (size_t)j;
    const float* cj = center + bj * 6;
    const float* lj = lrf    + bj * 9;

    f4u c03 = *(const f4u*)cj;              // cj[0..3]; [3] unused, in-row
    f4u l03 = *(const f4u*)lj;              // lj[0..3]
    f4u l47 = *(const f4u*)(lj + 4);        // lj[4..7]
    float l8 = lj[8];

    float d0 = c03.x - ci0, d1 = c03.y - ci1, d2 = c03.z - ci2;
    float lj_[9] = { l03.x, l03.y, l03.z, l03.w, l47.x, l47.y, l47.z, l47.w, l8 };

    // rel_pos[k] = sum_c d[c] * lrf_i[c][k]
#pragma unroll
    for (int k = 0; k < 3; ++k)
        s_pos[tid * 3 + k] = d0 * li_[k] + d1 * li_[3 + k] + d2 * li_[6 + k];

    // rel_ori[m][n] = sum_k lrf_i[k][m] * lrf_j[k][n]
#pragma unroll
    for (int m = 0; m < 3; ++m)
#pragma unroll
        for (int n = 0; n < 3; ++n)
            s_ori[tid * 9 + m * 3 + n] = li_[m]     * lj_[n]
                                       + li_[3 + m] * lj_[3 + n]
                                       + li_[6 + m] * lj_[6 + n];

    __syncthreads();

    // Fused writeback: 384 float4 = 3 per thread.
    const f4v* s4 = (const f4v*)s;
    f4v* op4 = (f4v*)out_pos + ((size_t)bi * 384  + (size_t)q * 96);
    f4v* oo4 = (f4v*)out_ori + ((size_t)bi * 1152 + (size_t)q * 288);

#pragma unroll
    for (int it = 0; it < 3; ++it) {
        int t = tid + (it << 7);
        if (t < 96) op4[t]      = s4[t];
        else        oo4[t - 96] = s4[t];
    }
}

extern "C" void kernel_launch(void* const* d_in, const int* in_sizes, int n_in,
                              void* d_out, int out_size, void* d_ws, size_t ws_size,
                              hipStream_t stream) {
    const float* center = (const float*)d_in[0];
    const float* lrf    = (const float*)d_in[1];
    float* out = (float*)d_out;

    const int B = 32;
    const size_t n_pos = (size_t)B * G_ * G_ * 3;   // 25,165,824 floats
    float* out_pos = out;
    float* out_ori = out + n_pos;

    dim3 grid(B * G_ * 4);   // 65536 one-shot quarter-row blocks
    dim3 block(128);
    hipLaunchKernelGGL(relposori_kernel, grid, block, 0, stream,
                       center, lrf, out_pos, out_ori);
}